// Round 3
// baseline (67.398 us; speedup 1.0000x reference)
//
#include <hip/hip_runtime.h>
#include <math.h>

#define B 8
#define N 2048
#define DIM 32
#define HID 64
#define KLIFT 16
#define DMODEL 256
#define KPROXY 16
#define KSEL 8.0f

typedef float f32x4 __attribute__((ext_vector_type(4)));
typedef short bf16x8 __attribute__((ext_vector_type(8)));

__device__ inline unsigned short f2bf(float f) {
  unsigned u = __float_as_uint(f);
  unsigned r = (u + 0x7FFFu + ((u >> 16) & 1u)) >> 16;  // RNE
  return (unsigned short)r;
}
__device__ inline float bf2f(unsigned short s) {
  return __uint_as_float(((unsigned)s) << 16);
}
__device__ inline float clip_temp(float lt) {
  return fminf(fmaxf(expf(lt), 0.1f), 10.f);
}

// ---------------- K1: saliency MLP + sq + bf16 hi/lo split + budget1 partials
__global__ __launch_bounds__(256) void k_prep(
    const float* __restrict__ x, const float* __restrict__ W1,
    const float* __restrict__ b1, const float* __restrict__ W2,
    const float* __restrict__ b2, const float* __restrict__ logt,
    float* __restrict__ sal, float* __restrict__ sq,
    unsigned short* __restrict__ Xhi, unsigned short* __restrict__ Xlo,
    float* __restrict__ partials1) {
  __shared__ float sW1[DIM * HID];
  __shared__ float sW2[HID], sb1[HID];
  __shared__ float red[4];
  int t = threadIdx.x;
  int lane = t & 63, wid = t >> 6;
  {
    const float4* s4 = (const float4*)W1;
    float4* d4 = (float4*)sW1;
    for (int i = t; i < DIM * HID / 4; i += 256) d4[i] = s4[i];
    if (t < HID) { sW2[t] = W2[t]; sb1[t] = b1[t]; }
  }
  __syncthreads();
  int p = blockIdx.x * 256 + t;       // 0..16383
  float xr[DIM];
  const float4* xp = (const float4*)(x + (size_t)p * DIM);
#pragma unroll
  for (int i = 0; i < DIM / 4; i++) {
    float4 v = xp[i];
    xr[4 * i + 0] = v.x; xr[4 * i + 1] = v.y; xr[4 * i + 2] = v.z; xr[4 * i + 3] = v.w;
  }
  float s = 0.f;
#pragma unroll
  for (int d = 0; d < DIM; d++) s = fmaf(xr[d], xr[d], s);
  sq[p] = s;
  float h[HID];
#pragma unroll
  for (int j = 0; j < HID; j++) h[j] = sb1[j];
  for (int d = 0; d < DIM; d++) {
    float xv = xr[d];
    const float4* wrow = (const float4*)(&sW1[d * HID]);
#pragma unroll
    for (int j4 = 0; j4 < HID / 4; j4++) {
      float4 w = wrow[j4];
      h[4 * j4 + 0] = fmaf(xv, w.x, h[4 * j4 + 0]);
      h[4 * j4 + 1] = fmaf(xv, w.y, h[4 * j4 + 1]);
      h[4 * j4 + 2] = fmaf(xv, w.z, h[4 * j4 + 2]);
      h[4 * j4 + 3] = fmaf(xv, w.w, h[4 * j4 + 3]);
    }
  }
  float acc = b2[0];
#pragma unroll
  for (int j = 0; j < HID; j++) acc = fmaf(fmaxf(h[j], 0.f), sW2[j], acc);
  sal[p] = acc;
  // budget1 partial: y0 = sigmoid((sal-0.5)/temp)
  float temp = clip_temp(logt[0]);
  float y0 = 1.f / (1.f + expf(-((acc - 0.5f) / temp)));
  float part = y0;
#pragma unroll
  for (int off = 32; off >= 1; off >>= 1) part += __shfl_xor(part, off);
  if (lane == 0) red[wid] = part;
  __syncthreads();
  if (t == 0) partials1[blockIdx.x] = red[0] + red[1] + red[2] + red[3];
  // fragment-order bf16 split: lane L = g*16+c of tile holds X[tile*16+c][g*8+j]
  int bb = p >> 11, n = p & (N - 1);
  int tile = n >> 4, c = n & 15;
  size_t tb = ((size_t)(bb * 128 + tile)) * 64;
#pragma unroll
  for (int g = 0; g < 4; g++) {
    bf16x8 hv, lv;
#pragma unroll
    for (int j = 0; j < 8; j++) {
      float v = xr[g * 8 + j];
      unsigned short hb = f2bf(v);
      hv[j] = (short)hb;
      lv[j] = (short)f2bf(v - bf2f(hb));
    }
    size_t off = (tb + (size_t)g * 16 + c) * 8;
    *(bf16x8*)(Xhi + off) = hv;
    *(bf16x8*)(Xlo + off) = lv;
  }
}

// ---------------- K2: NN distance (full-m per block, no atomics) + selector phase B
// grid = 8 b * 32 nchunks(64 rows). 4 waves; wave owns 1 n-tile (16 rows).
__global__ __launch_bounds__(256) void k_nnd(
    const unsigned short* __restrict__ Xhi, const unsigned short* __restrict__ Xlo,
    const float* __restrict__ sq, const float* __restrict__ sal,
    const float* __restrict__ x, const float* __restrict__ logt,
    const float* __restrict__ partials1,
    float* __restrict__ nnd2f, float* __restrict__ gpart) {
  int bid = blockIdx.x;
  int bb = bid >> 5, nch = bid & 31;
  int t = threadIdx.x, w = t >> 6, lane = t & 63;
  int c = lane & 15, g = lane >> 4;
  int ntile = nch * 4 + w;          // global n-tile 0..127
  __shared__ unsigned short ldsH[32 * 512];  // 512 m-rows, frag order (32 KB)
  __shared__ unsigned short ldsL[32 * 512];
  __shared__ float ssq[512];
  __shared__ float dvs[64], cs[64];
  __shared__ float gsh[8][32];
  bf16x8 ah = *(const bf16x8*)(Xhi + (((size_t)(bb * 128 + ntile)) * 64 + lane) * 8);
  bf16x8 al = *(const bf16x8*)(Xlo + (((size_t)(bb * 128 + ntile)) * 64 + lane) * 8);
  float mn[4] = {1e30f, 1e30f, 1e30f, 1e30f};
  for (int mc = 0; mc < 4; mc++) {
    __syncthreads();
    size_t base = ((size_t)(bb * 128 + mc * 32)) * 512;
    const float4* srcH = (const float4*)(Xhi + base);
    const float4* srcL = (const float4*)(Xlo + base);
    float4* dH = (float4*)ldsH;
    float4* dL = (float4*)ldsL;
    for (int i = t; i < 2048; i += 256) { dH[i] = srcH[i]; dL[i] = srcL[i]; }
    ssq[t] = sq[bb * N + mc * 512 + t];
    ssq[t + 256] = sq[bb * N + mc * 512 + t + 256];
    __syncthreads();
    for (int tt = 0; tt < 32; tt++) {
      bf16x8 bh = ((const bf16x8*)(ldsH + tt * 512))[lane];
      bf16x8 bl2 = ((const bf16x8*)(ldsL + tt * 512))[lane];
      f32x4 a0 = {0.f, 0.f, 0.f, 0.f};
      a0 = __builtin_amdgcn_mfma_f32_16x16x32_bf16(ah, bh, a0, 0, 0, 0);
      a0 = __builtin_amdgcn_mfma_f32_16x16x32_bf16(ah, bl2, a0, 0, 0, 0);
      a0 = __builtin_amdgcn_mfma_f32_16x16x32_bf16(al, bh, a0, 0, 0, 0);
      float sm = ssq[tt * 16 + c];
      int mtg = mc * 32 + tt;
      bool diag = (mtg == ntile);
#pragma unroll
      for (int r = 0; r < 4; r++) {
        float v = fmaf(-2.f, a0[r], sm);
        if (diag && c == 4 * g + r) v = 1e30f;   // mask self-distance
        mn[r] = fminf(mn[r], v);
      }
    }
  }
#pragma unroll
  for (int off = 1; off <= 8; off <<= 1) {
#pragma unroll
    for (int r = 0; r < 4; r++) mn[r] = fminf(mn[r], __shfl_xor(mn[r], off));
  }
  if (c == 0) {
#pragma unroll
    for (int r = 0; r < 4; r++) {
      int n0 = ntile * 16 + 4 * g + r;
      float d2 = fmaxf(sq[bb * N + n0] + mn[r], 0.f);
      nnd2f[bb * N + n0] = d2;
      dvs[w * 16 + 4 * g + r] = sqrtf(d2);
    }
  }
  __syncthreads();
  // ---- selector phase B: c_n = y1/nrm for this chunk's 64 points, partial g ----
  float temp = clip_temp(logt[0]);
  if (t < 64) {
    int n = nch * 64 + t;
    size_t basep = (size_t)bb * N + n;
    float b1v = 0.f;
    for (int j = 0; j < 8; j++) b1v += partials1[bb * 8 + j];
    float scale1 = fminf(KSEL / fmaxf(b1v, 1e-6f), 1.f);
    float sv = sal[basep];
    float y0 = 1.f / (1.f + expf(-((sv - 0.5f) / temp)));
    float y1 = y0 * scale1;
    float dv = dvs[t];
    float nrm = sqrtf(sq[basep] + 3.f * dv * dv + sv * sv) + 1e-8f;
    float cn = y1 / nrm;
    cs[t] = cn;
    float v32 = cn * dv, v33 = cn * sv;
#pragma unroll
    for (int off = 32; off >= 1; off >>= 1) {
      v32 += __shfl_xor(v32, off);
      v33 += __shfl_xor(v33, off);
    }
    if (t == 0) {
      gpart[(size_t)(bb * 32 + nch) * 36 + 32] = v32;
      gpart[(size_t)(bb * 32 + nch) * 36 + 33] = v33;
    }
  }
  __syncthreads();
  int d = t & 31, pg = t >> 5;
  float acc = 0.f;
#pragma unroll
  for (int i = 0; i < 8; i++)
    acc = fmaf(cs[pg * 8 + i], x[((size_t)bb * N + nch * 64 + pg * 8 + i) * DIM + d], acc);
  gsh[pg][d] = acc;
  __syncthreads();
  if (t < 32) {
    float s = 0.f;
#pragma unroll
    for (int pgi = 0; pgi < 8; pgi++) s += gsh[pgi][t];
    gpart[(size_t)(bb * 32 + nch) * 36 + t] = s;
  }
}

// ---------------- K3: y2 pass (1 point/thread) + budget2 partials ----------------
__global__ __launch_bounds__(256) void k_c(
    const float* __restrict__ x, const float* __restrict__ sal,
    const float* __restrict__ sq, const float* __restrict__ nnd2f,
    const float* __restrict__ logt, const float* __restrict__ partials1,
    const float* __restrict__ gpart, float* __restrict__ partials2,
    float* __restrict__ ystar) {
  int bid = blockIdx.x;
  int bb = bid >> 3, ch = bid & 7;
  int t = threadIdx.x, lane = t & 63, wid = t >> 6;
  __shared__ float gfin[34];
  __shared__ float s1sh;
  __shared__ float red[4];
  if (t < 34) {
    float s = 0.f;
    for (int j = 0; j < 32; j++) s += gpart[(size_t)(bb * 32 + j) * 36 + t];
    gfin[t] = s;
  }
  if (t == 40) {
    float s = 0.f;
    for (int j = 0; j < 8; j++) s += partials1[bb * 8 + j];
    s1sh = fminf(KSEL / fmaxf(s, 1e-6f), 1.f);
  }
  __syncthreads();
  float scale1 = s1sh;
  int n = ch * 256 + t;
  size_t base = (size_t)bb * N + n;
  float temp = clip_temp(logt[0]);
  float sv = sal[base];
  float y0 = 1.f / (1.f + expf(-((sv - 0.5f) / temp)));
  float y1 = y0 * scale1;
  float dv = sqrtf(nnd2f[base]);
  float nrm = sqrtf(sq[base] + 3.f * dv * dv + sv * sv) + 1e-8f;
  const float4* p4 = (const float4*)(x + base * DIM);
  float ov = 0.f;
#pragma unroll
  for (int cc = 0; cc < 8; cc++) {
    float4 v = p4[cc];
    ov = fmaf(v.x, gfin[4 * cc + 0], ov);
    ov = fmaf(v.y, gfin[4 * cc + 1], ov);
    ov = fmaf(v.z, gfin[4 * cc + 2], ov);
    ov = fmaf(v.w, gfin[4 * cc + 3], ov);
  }
  ov += 3.f * dv * gfin[32] + sv * gfin[33];
  ov /= nrm;
  float y2 = y1 / (1.f + ov);
  ystar[base] = y2;              // unscaled; k_post applies scale2
  float part = y2;
#pragma unroll
  for (int off = 32; off >= 1; off >>= 1) part += __shfl_xor(part, off);
  if (lane == 0) red[wid] = part;
  __syncthreads();
  if (t == 0) partials2[bb * 8 + ch] = red[0] + red[1] + red[2] + red[3];
}

// ---------------- K4: scale2 + ystar + top-16 + tokens ----------------
__global__ __launch_bounds__(512) void k_post(
    const float* __restrict__ x, const float* __restrict__ nnd2f,
    const float* __restrict__ partials2, const float* __restrict__ mu,
    const float* __restrict__ sigma, const float* __restrict__ Wl,
    const float* __restrict__ bl, const float* __restrict__ Wp,
    const float* __restrict__ bp, float* __restrict__ tok,
    float* __restrict__ ystar) {
  int b = blockIdx.x, t = threadIdx.x;
  int lane = t & 63, wid = t >> 6;
  __shared__ float yv[N];
  __shared__ float bsh;
  __shared__ float candv[128];
  __shared__ int candi[128];
  __shared__ int tix[KPROXY];
  __shared__ float sz[KPROXY][36];
  if (t == 0) {
    float s = 0.f;
    for (int j = 0; j < 8; j++) s += partials2[b * 8 + j];
    bsh = fminf(KSEL / fmaxf(s, 1e-6f), 1.f);
  }
  __syncthreads();
  float scale2 = bsh;
#pragma unroll
  for (int i = 0; i < 4; i++) {
    int n = t + 512 * i;
    float y = ystar[(size_t)b * N + n] * scale2;
    yv[n] = y;
    ystar[(size_t)b * N + n] = y;
  }
  __syncthreads();
  // ---- top-16 stage 1: per-wave top-16 of its 256 elems (ties -> lower index) ----
  float lv0 = yv[wid * 256 + lane];        int li0 = wid * 256 + lane;
  float lv1 = yv[wid * 256 + 64 + lane];   int li1 = li0 + 64;
  float lv2 = yv[wid * 256 + 128 + lane];  int li2 = li0 + 128;
  float lv3 = yv[wid * 256 + 192 + lane];  int li3 = li0 + 192;
  for (int r = 0; r < KPROXY; r++) {
    float bv = lv0; int bi = li0;
    if (lv1 > bv) { bv = lv1; bi = li1; }
    if (lv2 > bv) { bv = lv2; bi = li2; }
    if (lv3 > bv) { bv = lv3; bi = li3; }
#pragma unroll
    for (int off = 1; off < 64; off <<= 1) {
      float ovv = __shfl_xor(bv, off);
      int oi = __shfl_xor(bi, off);
      if (ovv > bv || (ovv == bv && oi < bi)) { bv = ovv; bi = oi; }
    }
    if (lane == 0) { candv[wid * 16 + r] = bv; candi[wid * 16 + r] = bi; }
    if (li0 == bi) lv0 = -1e30f;
    if (li1 == bi) lv1 = -1e30f;
    if (li2 == bi) lv2 = -1e30f;
    if (li3 == bi) lv3 = -1e30f;
  }
  __syncthreads();
  // ---- stage 2: wave 0 merges 128 candidates ----
  if (wid == 0) {
    float cv0 = candv[lane], cv1 = candv[lane + 64];
    int ci0 = candi[lane], ci1 = candi[lane + 64];
    for (int r = 0; r < KPROXY; r++) {
      float bv = cv0; int bi = ci0;
      if (cv1 > bv || (cv1 == bv && ci1 < bi)) { bv = cv1; bi = ci1; }
#pragma unroll
      for (int off = 1; off < 64; off <<= 1) {
        float ovv = __shfl_xor(bv, off);
        int oi = __shfl_xor(bi, off);
        if (ovv > bv || (ovv == bv && oi < bi)) { bv = ovv; bi = oi; }
      }
      if (lane == 0) tix[r] = bi;
      if (ci0 == bi) cv0 = -1e30f;
      if (ci1 == bi) cv1 = -1e30f;
    }
  }
  __syncthreads();
  // ---- tokens: one wave per selected row, 2 rounds ----
  for (int it = 0; it < 2; it++) {
    int k = wid + 8 * it;
    int srow = tix[k];
    if (lane < 36) {
      float f;
      if (lane < 32) f = x[((size_t)b * N + srow) * DIM + lane];
      else if (lane < 35) f = sqrtf(nnd2f[b * N + srow]);
      else f = 0.f;   // std of single NN distance is exactly 0
      sz[k][lane] = (f - mu[lane]) / sigma[lane];
    }
    __syncthreads();
    float lf = 0.f;
    if (lane < KLIFT) {
      float a = bl[lane];
#pragma unroll
      for (int d = 0; d < 36; d++) a = fmaf(sz[k][d], Wl[d * KLIFT + lane], a);
      lf = tanhf(a);
    }
    float o0 = bp[lane], o1 = bp[lane + 64], o2 = bp[lane + 128], o3 = bp[lane + 192];
#pragma unroll
    for (int j = 0; j < KLIFT; j++) {
      float lj = __shfl(lf, j);
      const float* wr = Wp + j * DMODEL + lane;
      o0 = fmaf(lj, wr[0], o0);
      o1 = fmaf(lj, wr[64], o1);
      o2 = fmaf(lj, wr[128], o2);
      o3 = fmaf(lj, wr[192], o3);
    }
    float* tp = tok + ((size_t)b * KPROXY + k) * DMODEL + lane;
    tp[0] = o0; tp[64] = o1; tp[128] = o2; tp[192] = o3;
  }
}

extern "C" void kernel_launch(void* const* d_in, const int* in_sizes, int n_in,
                              void* d_out, int out_size, void* d_ws, size_t ws_size,
                              hipStream_t stream) {
  const float* x  = (const float*)d_in[0];
  const float* lt = (const float*)d_in[1];
  const float* W1 = (const float*)d_in[2];
  const float* b1 = (const float*)d_in[3];
  const float* W2 = (const float*)d_in[4];
  const float* b2 = (const float*)d_in[5];
  const float* mu = (const float*)d_in[6];
  const float* sg = (const float*)d_in[7];
  const float* Wl = (const float*)d_in[8];
  const float* bl = (const float*)d_in[9];
  const float* Wp = (const float*)d_in[10];
  const float* bp = (const float*)d_in[11];

  float* tok = (float*)d_out;
  float* ystar = tok + B * KPROXY * DMODEL;

  char* ws = (char*)d_ws;
  float* sal          = (float*)(ws);                    // 64 KB
  float* sq           = (float*)(ws + 65536);            // 64 KB
  float* nnd2f        = (float*)(ws + 131072);           // 64 KB
  float* partials1    = (float*)(ws + 196608);           // 64 f
  float* gpart        = (float*)(ws + 197120);           // 8*32*36 f = 36 KB
  float* partials2    = (float*)(ws + 234496);           // 64 f
  unsigned short* Xhi = (unsigned short*)(ws + 262144);  // 1 MB
  unsigned short* Xlo = (unsigned short*)(ws + 262144 + 1048576); // 1 MB

  k_prep<<<B * N / 256, 256, 0, stream>>>(x, W1, b1, W2, b2, lt, sal, sq, Xhi, Xlo, partials1);
  k_nnd<<<B * 32, 256, 0, stream>>>(Xhi, Xlo, sq, sal, x, lt, partials1, nnd2f, gpart);
  k_c<<<B * 8, 256, 0, stream>>>(x, sal, sq, nnd2f, lt, partials1, gpart, partials2, ystar);
  k_post<<<B, 512, 0, stream>>>(x, nnd2f, partials2, mu, sg, Wl, bl, Wp, bp, tok, ystar);
}

// Round 4
// 60.185 us; speedup vs baseline: 1.1199x; 1.1199x over previous
//
#include <hip/hip_runtime.h>
#include <math.h>

#define B 8
#define N 2048
#define DIM 32
#define HID 64
#define KLIFT 16
#define DMODEL 256
#define KPROXY 16
#define KSEL 8.0f

typedef float f32x4 __attribute__((ext_vector_type(4)));
typedef short bf16x8 __attribute__((ext_vector_type(8)));

__device__ inline unsigned short f2bf(float f) {
  unsigned u = __float_as_uint(f);
  unsigned r = (u + 0x7FFFu + ((u >> 16) & 1u)) >> 16;  // RNE
  return (unsigned short)r;
}
__device__ inline float bf2f(unsigned short s) {
  return __uint_as_float(((unsigned)s) << 16);
}
__device__ inline float clip_temp(float lt) {
  return fminf(fmaxf(expf(lt), 0.1f), 10.f);
}

// ---------------- K1: saliency MLP + sq + bf16 hi/lo split + budget1 partials + nnd2 init
__global__ __launch_bounds__(256) void k_prep(
    const float* __restrict__ x, const float* __restrict__ W1,
    const float* __restrict__ b1, const float* __restrict__ W2,
    const float* __restrict__ b2, const float* __restrict__ logt,
    float* __restrict__ sal, float* __restrict__ sq,
    unsigned short* __restrict__ Xhi, unsigned short* __restrict__ Xlo,
    float* __restrict__ partials1, unsigned* __restrict__ nnd2) {
  __shared__ float sW1[DIM * HID];
  __shared__ float sW2[HID], sb1[HID];
  __shared__ float red[4];
  int t = threadIdx.x;
  int lane = t & 63, wid = t >> 6;
  {
    const float4* s4 = (const float4*)W1;
    float4* d4 = (float4*)sW1;
    for (int i = t; i < DIM * HID / 4; i += 256) d4[i] = s4[i];
    if (t < HID) { sW2[t] = W2[t]; sb1[t] = b1[t]; }
  }
  __syncthreads();
  int p = blockIdx.x * 256 + t;       // 0..16383
  nnd2[p] = 0x7F7F7F7Fu;              // huge positive float bits
  float xr[DIM];
  const float4* xp = (const float4*)(x + (size_t)p * DIM);
#pragma unroll
  for (int i = 0; i < DIM / 4; i++) {
    float4 v = xp[i];
    xr[4 * i + 0] = v.x; xr[4 * i + 1] = v.y; xr[4 * i + 2] = v.z; xr[4 * i + 3] = v.w;
  }
  float s = 0.f;
#pragma unroll
  for (int d = 0; d < DIM; d++) s = fmaf(xr[d], xr[d], s);
  sq[p] = s;
  float h[HID];
#pragma unroll
  for (int j = 0; j < HID; j++) h[j] = sb1[j];
  for (int d = 0; d < DIM; d++) {
    float xv = xr[d];
    const float4* wrow = (const float4*)(&sW1[d * HID]);
#pragma unroll
    for (int j4 = 0; j4 < HID / 4; j4++) {
      float4 w = wrow[j4];
      h[4 * j4 + 0] = fmaf(xv, w.x, h[4 * j4 + 0]);
      h[4 * j4 + 1] = fmaf(xv, w.y, h[4 * j4 + 1]);
      h[4 * j4 + 2] = fmaf(xv, w.z, h[4 * j4 + 2]);
      h[4 * j4 + 3] = fmaf(xv, w.w, h[4 * j4 + 3]);
    }
  }
  float acc = b2[0];
#pragma unroll
  for (int j = 0; j < HID; j++) acc = fmaf(fmaxf(h[j], 0.f), sW2[j], acc);
  sal[p] = acc;
  // budget1 partial
  float temp = clip_temp(logt[0]);
  float y0 = 1.f / (1.f + expf(-((acc - 0.5f) / temp)));
  float part = y0;
#pragma unroll
  for (int off = 32; off >= 1; off >>= 1) part += __shfl_xor(part, off);
  if (lane == 0) red[wid] = part;
  __syncthreads();
  if (t == 0) partials1[blockIdx.x] = red[0] + red[1] + red[2] + red[3];
  // fragment-order bf16 split: lane L = g*16+c of tile holds X[tile*16+c][g*8+j]
  int bb = p >> 11, n = p & (N - 1);
  int tile = n >> 4, c = n & 15;
  size_t tb = ((size_t)(bb * 128 + tile)) * 64;
#pragma unroll
  for (int g = 0; g < 4; g++) {
    bf16x8 hv, lv;
#pragma unroll
    for (int j = 0; j < 8; j++) {
      float v = xr[g * 8 + j];
      unsigned short hb = f2bf(v);
      hv[j] = (short)hb;
      lv[j] = (short)f2bf(v - bf2f(hb));
    }
    size_t off = (tb + (size_t)g * 16 + c) * 8;
    *(bf16x8*)(Xhi + off) = hv;
    *(bf16x8*)(Xlo + off) = lv;
  }
}

// ---------------- K2: NN squared distance via split-bf16 MFMA Gram ----------------
// grid = 8 b * 16 nchunks(128 rows) * 8 moctiles(256 rows) = 1024 blocks (4/CU).
// wave owns 2 n-tiles (2 independent MFMA chains); 16 tt iterations.
__global__ __launch_bounds__(256) void k_nnd(
    const unsigned short* __restrict__ Xhi, const unsigned short* __restrict__ Xlo,
    const float* __restrict__ sq, unsigned* __restrict__ nnd2) {
  int bid = blockIdx.x;
  int bb = bid >> 7;
  int nch = (bid >> 3) & 15;
  int mo = bid & 7;
  int t = threadIdx.x;
  int w = t >> 6, lane = t & 63;
  int c = lane & 15, g = lane >> 4;
  __shared__ unsigned short ldsH[16 * 512];  // 16 m-tiles, frag order (16 KB)
  __shared__ unsigned short ldsL[16 * 512];
  __shared__ float ssq[256];
  {
    size_t base = ((size_t)(bb * 128 + mo * 16)) * 512;
    const float4* srcH = (const float4*)(Xhi + base);
    const float4* srcL = (const float4*)(Xlo + base);
    float4* dH = (float4*)ldsH;
    float4* dL = (float4*)ldsL;
    for (int i = t; i < 1024; i += 256) { dH[i] = srcH[i]; dL[i] = srcL[i]; }
    ssq[t] = sq[bb * N + mo * 256 + t];
  }
  int nt0 = nch * 8 + w * 2, nt1 = nt0 + 1;
  bf16x8 ah0 = *(const bf16x8*)(Xhi + (((size_t)(bb * 128 + nt0)) * 64 + lane) * 8);
  bf16x8 al0 = *(const bf16x8*)(Xlo + (((size_t)(bb * 128 + nt0)) * 64 + lane) * 8);
  bf16x8 ah1 = *(const bf16x8*)(Xhi + (((size_t)(bb * 128 + nt1)) * 64 + lane) * 8);
  bf16x8 al1 = *(const bf16x8*)(Xlo + (((size_t)(bb * 128 + nt1)) * 64 + lane) * 8);
  __syncthreads();
  float mn0[4] = {1e30f, 1e30f, 1e30f, 1e30f};
  float mn1[4] = {1e30f, 1e30f, 1e30f, 1e30f};
  for (int tt = 0; tt < 16; tt++) {
    bf16x8 bh = ((const bf16x8*)(ldsH + tt * 512))[lane];
    bf16x8 bl2 = ((const bf16x8*)(ldsL + tt * 512))[lane];
    f32x4 a0 = {0.f, 0.f, 0.f, 0.f};
    f32x4 a1 = {0.f, 0.f, 0.f, 0.f};
    a0 = __builtin_amdgcn_mfma_f32_16x16x32_bf16(ah0, bh, a0, 0, 0, 0);
    a1 = __builtin_amdgcn_mfma_f32_16x16x32_bf16(ah1, bh, a1, 0, 0, 0);
    a0 = __builtin_amdgcn_mfma_f32_16x16x32_bf16(ah0, bl2, a0, 0, 0, 0);
    a1 = __builtin_amdgcn_mfma_f32_16x16x32_bf16(ah1, bl2, a1, 0, 0, 0);
    a0 = __builtin_amdgcn_mfma_f32_16x16x32_bf16(al0, bh, a0, 0, 0, 0);
    a1 = __builtin_amdgcn_mfma_f32_16x16x32_bf16(al1, bh, a1, 0, 0, 0);
    float sm = ssq[tt * 16 + c];
    int mtg = mo * 16 + tt;
    bool d0 = (mtg == nt0), d1 = (mtg == nt1);
#pragma unroll
    for (int r = 0; r < 4; r++) {
      float v0 = fmaf(-2.f, a0[r], sm);
      float v1 = fmaf(-2.f, a1[r], sm);
      if (d0 && c == 4 * g + r) v0 = 1e30f;   // mask self-distance
      if (d1 && c == 4 * g + r) v1 = 1e30f;
      mn0[r] = fminf(mn0[r], v0);
      mn1[r] = fminf(mn1[r], v1);
    }
  }
#pragma unroll
  for (int off = 1; off <= 8; off <<= 1) {
#pragma unroll
    for (int r = 0; r < 4; r++) {
      mn0[r] = fminf(mn0[r], __shfl_xor(mn0[r], off));
      mn1[r] = fminf(mn1[r], __shfl_xor(mn1[r], off));
    }
  }
  if (c == 0) {
#pragma unroll
    for (int r = 0; r < 4; r++) {
      int n0 = nt0 * 16 + 4 * g + r;
      float v = fmaxf(sq[bb * N + n0] + mn0[r], 0.f);
      atomicMin(&nnd2[bb * N + n0], __float_as_uint(v));
      int n1 = nt1 * 16 + 4 * g + r;
      v = fmaxf(sq[bb * N + n1] + mn1[r], 0.f);
      atomicMin(&nnd2[bb * N + n1], __float_as_uint(v));
    }
  }
}

// ---------------- K3: selector phase B — cn and partial g per 256-pt chunk ----------------
__global__ __launch_bounds__(256) void k_c1(
    const float* __restrict__ x, const float* __restrict__ sal,
    const float* __restrict__ sq, const unsigned* __restrict__ nnd2,
    const float* __restrict__ logt, const float* __restrict__ partials1,
    float* __restrict__ gpart) {
  int bid = blockIdx.x;
  int bb = bid >> 3, ch = bid & 7;
  int t = threadIdx.x, lane = t & 63, wid = t >> 6;
  __shared__ float xs[256][33];   // padded: column reads conflict-free
  __shared__ float cs[256];
  __shared__ float gsh[8][32];
  __shared__ float red32[4], red33[4];
  int n = ch * 256 + t;
  size_t base = (size_t)bb * N + n;
  float temp = clip_temp(logt[0]);
  float b1v = 0.f;
  for (int j = 0; j < 8; j++) b1v += partials1[bb * 8 + j];
  float scale1 = fminf(KSEL / fmaxf(b1v, 1e-6f), 1.f);
  float sv = sal[base];
  float y0 = 1.f / (1.f + expf(-((sv - 0.5f) / temp)));
  float y1 = y0 * scale1;
  float dv = sqrtf(__uint_as_float(nnd2[base]));
  float nrm = sqrtf(sq[base] + 3.f * dv * dv + sv * sv) + 1e-8f;
  float cn = y1 / nrm;
  cs[t] = cn;
  // stage x tile (coalesced read, padded LDS write)
  {
    const float4* xsrc = (const float4*)(x + ((size_t)bb * N + ch * 256) * DIM);
    for (int j = t; j < 2048; j += 256) {
      float4 v = xsrc[j];
      int pt = j >> 3, c4 = (j & 7) * 4;
      xs[pt][c4 + 0] = v.x; xs[pt][c4 + 1] = v.y;
      xs[pt][c4 + 2] = v.z; xs[pt][c4 + 3] = v.w;
    }
  }
  // partials for g[32] (d comp) and g[33] (sal comp)
  float v32 = cn * dv, v33 = cn * sv;
#pragma unroll
  for (int off = 32; off >= 1; off >>= 1) {
    v32 += __shfl_xor(v32, off);
    v33 += __shfl_xor(v33, off);
  }
  if (lane == 0) { red32[wid] = v32; red33[wid] = v33; }
  __syncthreads();
  if (t == 0) {
    gpart[(size_t)(bb * 8 + ch) * 36 + 32] = red32[0] + red32[1] + red32[2] + red32[3];
    gpart[(size_t)(bb * 8 + ch) * 36 + 33] = red33[0] + red33[1] + red33[2] + red33[3];
  }
  // g[0..31]: thread (pg, d) accumulates 32 points
  int d = t & 31, pg = t >> 5;
  float acc = 0.f;
#pragma unroll
  for (int i = 0; i < 32; i++) acc = fmaf(cs[pg * 32 + i], xs[pg * 32 + i][d], acc);
  gsh[pg][d] = acc;
  __syncthreads();
  if (t < 32) {
    float s = 0.f;
#pragma unroll
    for (int pgi = 0; pgi < 8; pgi++) s += gsh[pgi][t];
    gpart[(size_t)(bb * 8 + ch) * 36 + t] = s;
  }
}

// ---------------- K4: y2 pass (1 point/thread) + budget2 partials ----------------
__global__ __launch_bounds__(256) void k_c(
    const float* __restrict__ x, const float* __restrict__ sal,
    const float* __restrict__ sq, const unsigned* __restrict__ nnd2,
    const float* __restrict__ logt, const float* __restrict__ partials1,
    const float* __restrict__ gpart, float* __restrict__ partials2,
    float* __restrict__ ystar) {
  int bid = blockIdx.x;
  int bb = bid >> 3, ch = bid & 7;
  int t = threadIdx.x, lane = t & 63, wid = t >> 6;
  __shared__ float gfin[34];
  __shared__ float s1sh;
  __shared__ float red[4];
  if (t < 34) {
    float s = 0.f;
    for (int j = 0; j < 8; j++) s += gpart[(size_t)(bb * 8 + j) * 36 + t];
    gfin[t] = s;
  }
  if (t == 40) {
    float s = 0.f;
    for (int j = 0; j < 8; j++) s += partials1[bb * 8 + j];
    s1sh = fminf(KSEL / fmaxf(s, 1e-6f), 1.f);
  }
  __syncthreads();
  float scale1 = s1sh;
  int n = ch * 256 + t;
  size_t base = (size_t)bb * N + n;
  float temp = clip_temp(logt[0]);
  float sv = sal[base];
  float y0 = 1.f / (1.f + expf(-((sv - 0.5f) / temp)));
  float y1 = y0 * scale1;
  float dv = sqrtf(__uint_as_float(nnd2[base]));
  float nrm = sqrtf(sq[base] + 3.f * dv * dv + sv * sv) + 1e-8f;
  const float4* p4 = (const float4*)(x + base * DIM);
  float ov = 0.f;
#pragma unroll
  for (int cc = 0; cc < 8; cc++) {
    float4 v = p4[cc];
    ov = fmaf(v.x, gfin[4 * cc + 0], ov);
    ov = fmaf(v.y, gfin[4 * cc + 1], ov);
    ov = fmaf(v.z, gfin[4 * cc + 2], ov);
    ov = fmaf(v.w, gfin[4 * cc + 3], ov);
  }
  ov += 3.f * dv * gfin[32] + sv * gfin[33];
  ov /= nrm;
  float y2 = y1 / (1.f + ov);
  ystar[base] = y2;              // unscaled; k_post applies scale2
  float part = y2;
#pragma unroll
  for (int off = 32; off >= 1; off >>= 1) part += __shfl_xor(part, off);
  if (lane == 0) red[wid] = part;
  __syncthreads();
  if (t == 0) partials2[bb * 8 + ch] = red[0] + red[1] + red[2] + red[3];
}

// ---------------- K5: scale2 + ystar + top-16 + tokens ----------------
__global__ __launch_bounds__(512) void k_post(
    const float* __restrict__ x, const unsigned* __restrict__ nnd2,
    const float* __restrict__ partials2, const float* __restrict__ mu,
    const float* __restrict__ sigma, const float* __restrict__ Wl,
    const float* __restrict__ bl, const float* __restrict__ Wp,
    const float* __restrict__ bp, float* __restrict__ tok,
    float* __restrict__ ystar) {
  int b = blockIdx.x, t = threadIdx.x;
  int lane = t & 63, wid = t >> 6;
  __shared__ float yv[N];
  __shared__ float bsh;
  __shared__ float candv[128];
  __shared__ int candi[128];
  __shared__ int tix[KPROXY];
  __shared__ float sz[KPROXY][36];
  if (t == 0) {
    float s = 0.f;
    for (int j = 0; j < 8; j++) s += partials2[b * 8 + j];
    bsh = fminf(KSEL / fmaxf(s, 1e-6f), 1.f);
  }
  __syncthreads();
  float scale2 = bsh;
#pragma unroll
  for (int i = 0; i < 4; i++) {
    int n = t + 512 * i;
    float y = ystar[(size_t)b * N + n] * scale2;
    yv[n] = y;
    ystar[(size_t)b * N + n] = y;
  }
  __syncthreads();
  // ---- top-16 stage 1: per-wave top-16 of its 256 elems (ties -> lower index) ----
  float lv0 = yv[wid * 256 + lane];        int li0 = wid * 256 + lane;
  float lv1 = yv[wid * 256 + 64 + lane];   int li1 = li0 + 64;
  float lv2 = yv[wid * 256 + 128 + lane];  int li2 = li0 + 128;
  float lv3 = yv[wid * 256 + 192 + lane];  int li3 = li0 + 192;
  for (int r = 0; r < KPROXY; r++) {
    float bv = lv0; int bi = li0;
    if (lv1 > bv) { bv = lv1; bi = li1; }
    if (lv2 > bv) { bv = lv2; bi = li2; }
    if (lv3 > bv) { bv = lv3; bi = li3; }
#pragma unroll
    for (int off = 1; off < 64; off <<= 1) {
      float ovv = __shfl_xor(bv, off);
      int oi = __shfl_xor(bi, off);
      if (ovv > bv || (ovv == bv && oi < bi)) { bv = ovv; bi = oi; }
    }
    if (lane == 0) { candv[wid * 16 + r] = bv; candi[wid * 16 + r] = bi; }
    if (li0 == bi) lv0 = -1e30f;
    if (li1 == bi) lv1 = -1e30f;
    if (li2 == bi) lv2 = -1e30f;
    if (li3 == bi) lv3 = -1e30f;
  }
  __syncthreads();
  // ---- stage 2: wave 0 merges 128 candidates ----
  if (wid == 0) {
    float cv0 = candv[lane], cv1 = candv[lane + 64];
    int ci0 = candi[lane], ci1 = candi[lane + 64];
    for (int r = 0; r < KPROXY; r++) {
      float bv = cv0; int bi = ci0;
      if (cv1 > bv || (cv1 == bv && ci1 < bi)) { bv = cv1; bi = ci1; }
#pragma unroll
      for (int off = 1; off < 64; off <<= 1) {
        float ovv = __shfl_xor(bv, off);
        int oi = __shfl_xor(bi, off);
        if (ovv > bv || (ovv == bv && oi < bi)) { bv = ovv; bi = oi; }
      }
      if (lane == 0) tix[r] = bi;
      if (ci0 == bi) cv0 = -1e30f;
      if (ci1 == bi) cv1 = -1e30f;
    }
  }
  __syncthreads();
  // ---- tokens: one wave per selected row, 2 rounds ----
  for (int it = 0; it < 2; it++) {
    int k = wid + 8 * it;
    int srow = tix[k];
    if (lane < 36) {
      float f;
      if (lane < 32) f = x[((size_t)b * N + srow) * DIM + lane];
      else if (lane < 35) f = sqrtf(__uint_as_float(nnd2[b * N + srow]));
      else f = 0.f;   // std of single NN distance is exactly 0
      sz[k][lane] = (f - mu[lane]) / sigma[lane];
    }
    __syncthreads();
    float lf = 0.f;
    if (lane < KLIFT) {
      float a = bl[lane];
#pragma unroll
      for (int d = 0; d < 36; d++) a = fmaf(sz[k][d], Wl[d * KLIFT + lane], a);
      lf = tanhf(a);
    }
    float o0 = bp[lane], o1 = bp[lane + 64], o2 = bp[lane + 128], o3 = bp[lane + 192];
#pragma unroll
    for (int j = 0; j < KLIFT; j++) {
      float lj = __shfl(lf, j);
      const float* wr = Wp + j * DMODEL + lane;
      o0 = fmaf(lj, wr[0], o0);
      o1 = fmaf(lj, wr[64], o1);
      o2 = fmaf(lj, wr[128], o2);
      o3 = fmaf(lj, wr[192], o3);
    }
    float* tp = tok + ((size_t)b * KPROXY + k) * DMODEL + lane;
    tp[0] = o0; tp[64] = o1; tp[128] = o2; tp[192] = o3;
  }
}

extern "C" void kernel_launch(void* const* d_in, const int* in_sizes, int n_in,
                              void* d_out, int out_size, void* d_ws, size_t ws_size,
                              hipStream_t stream) {
  const float* x  = (const float*)d_in[0];
  const float* lt = (const float*)d_in[1];
  const float* W1 = (const float*)d_in[2];
  const float* b1 = (const float*)d_in[3];
  const float* W2 = (const float*)d_in[4];
  const float* b2 = (const float*)d_in[5];
  const float* mu = (const float*)d_in[6];
  const float* sg = (const float*)d_in[7];
  const float* Wl = (const float*)d_in[8];
  const float* bl = (const float*)d_in[9];
  const float* Wp = (const float*)d_in[10];
  const float* bp = (const float*)d_in[11];

  float* tok = (float*)d_out;
  float* ystar = tok + B * KPROXY * DMODEL;

  char* ws = (char*)d_ws;
  float* sal          = (float*)(ws);                    // 64 KB
  float* sq           = (float*)(ws + 65536);            // 64 KB
  unsigned* nnd2      = (unsigned*)(ws + 131072);        // 64 KB (float bits)
  float* partials1    = (float*)(ws + 196608);           // 64 f
  float* gpart        = (float*)(ws + 197120);           // 8*8*36 f
  float* partials2    = (float*)(ws + 231424);           // 64 f
  unsigned short* Xhi = (unsigned short*)(ws + 262144);  // 1 MB
  unsigned short* Xlo = (unsigned short*)(ws + 262144 + 1048576); // 1 MB

  k_prep<<<B * N / 256, 256, 0, stream>>>(x, W1, b1, W2, b2, lt, sal, sq, Xhi, Xlo, partials1, nnd2);
  k_nnd<<<B * 16 * 8, 256, 0, stream>>>(Xhi, Xlo, sq, nnd2);
  k_c1<<<B * 8, 256, 0, stream>>>(x, sal, sq, nnd2, lt, partials1, gpart);
  k_c<<<B * 8, 256, 0, stream>>>(x, sal, sq, nnd2, lt, partials1, gpart, partials2, ystar);
  k_post<<<B, 512, 0, stream>>>(x, nnd2, partials2, mu, sg, Wl, bl, Wp, bp, tok, ystar);
}